// Round 7
// baseline (86.988 us; speedup 1.0000x reference)
//
#include <hip/hip_runtime.h>
#include <math.h>

#define MM 63
#define NN 127
#define BB 256
#define NIT 3
#define CSRB 68        // byte list per check row (cnt<=64 proven r5)
#define CSCB 44        // byte list per column (proven r4)
#define PQS 65         // float2 slots per (v,s) group
#define WLV 112        // u16 slots per (n,variant): Lv ~ 68+-7.2, cap = mu+6sigma
#define WLN (2*WLV)

__global__ __launch_bounds__(1024)
void decode_kernel(const float* __restrict__ soft_in,
                   const int* __restrict__ labels,
                   const float* __restrict__ Hg,
                   const float* __restrict__ cw,
                   float* __restrict__ out)
{
    const int b   = blockIdx.x;
    const int tid = threadIdx.x;

    __shared__ unsigned char csr[MM][CSRB];
    __shared__ unsigned char csc[NN][CSCB];
    __shared__ int   rcnt[MM], ccnt[NN];
    __shared__ short lvn[NN][2];            // Lv per (n, variant)
    __shared__ float base0[128];            // [127] = 1e30 sentinel
    __shared__ float2 pqf[8 * PQS];         // slot 63 = (0,0) sentinel
    __shared__ unsigned short wl[NN * WLN]; // pre-decoded pq byte-addresses
    __shared__ float hist[NIT][NN];
    __shared__ float red2[2];

    // ---------------- prologue ----------------
    {
        unsigned int* wlw = (unsigned int*)wl;
        for (int i = tid; i < NN * WLN / 2; i += 1024)
            wlw[i] = 0x01F801F8u;                    // sentinel addr 504 = pqf[63]
    }
    if (tid < MM) rcnt[tid] = 0;
    if (tid < NN) ccnt[tid] = 0;
    float lf = 0.0f;
    if (tid < NN) {
        float v = soft_in[b * NN + tid];
        base0[tid] = v;
        out[b * NN + tid] = v;                       // outs[0]
        lf = (float)labels[b * NN + tid];            // prefetch for loss
    }
    if (tid == NN)  base0[127] = 1e30f;
    if (tid == 128) pqf[63] = make_float2(0.0f, 0.0f);
    const float spw = log1pf(expf(cw[0]));           // softplus(check_weight)
    __syncthreads();

    // ---- build CSR/CSC: coalesced H scan + LDS atomic append ----
    for (int i = tid; i < MM * NN; i += 1024) {
        if (Hg[i] != 0.0f) {
            int m = i / NN;
            int c = i - m * NN;
            csr[m][atomicAdd(&rcnt[m], 1)] = (unsigned char)c;
            csc[c][atomicAdd(&ccnt[c], 1)] = (unsigned char)m;
        }
    }
    __syncthreads();

    // ---- build worklist: per (n,v) concat of 4 shift-lists as pq byte-addrs;
    //      record Lv for dynamic chunking ----
    if (tid < NN * 8) {
        const int n = tid >> 3, v = (tid >> 2) & 1, s = tid & 3;
        const int p0 = v ? (n * 64) % NN : n;
        const int bbase = n * WLN + v * WLV;
        int off = bbase;
        for (int s2 = 0; s2 < s; ++s2) {
            int j2 = p0 + 31 * s2; if (j2 >= NN) j2 -= NN;
            off += ccnt[j2];
        }
        int j = p0 + 31 * s; if (j >= NN) j -= NN;
        const int cc = ccnt[j];
        const int gb = ((v * 4 + s) * PQS) * 8;      // group base, bytes
        for (int i = 0; i < cc; ++i)
            wl[off + i] = (unsigned short)(gb + csc[j][i] * 8);
        if (s == 3) lvn[n][v] = (short)(off + cc - bbase);   // Lv
    }

    // ---- hoist Phase A: pre-decoded base0 byte-addresses, u16-packed ----
    unsigned int apk[16];
    int aW = 0, pqslot = 0;
    {
        const int vs = tid >> 7, mslot = (tid >> 1) & 63, half = tid & 1;
        if (mslot < MM) {
            const int v = vs >> 2, shift = (vs & 3) * 31;
            const int cnt   = rcnt[mslot];
            const int hcnt  = (cnt + 1) >> 1;
            const int start = half ? hcnt : 0;
            const int mycnt = half ? (cnt - hcnt) : hcnt;
            aW = (mycnt + 3) >> 2;
            pqslot = vs * PQS + mslot;
            #pragma unroll
            for (int g = 0; g < 8; ++g) {
                unsigned int w0 = 0x01FC01FCu, w1 = 0x01FC01FCu; // sentinel 508
                if (g < aW) {
                    unsigned int ad[4];
                    #pragma unroll
                    for (int jj = 0; jj < 4; ++jj) {
                        int e = 4 * g + jj;
                        int addr = 508;                          // base0[127]
                        if (e < mycnt) {
                            int c = csr[mslot][start + e];
                            int t = c - shift; t += (t < 0) ? NN : 0;  // roll
                            if (v) { t <<= 1; t -= (t >= NN) ? NN : 0; } // perm
                            addr = t * 4;
                        }
                        ad[jj] = (unsigned int)addr;
                    }
                    w0 = ad[0] | (ad[1] << 16);
                    w1 = ad[2] | (ad[3] << 16);
                }
                apk[2 * g] = w0; apk[2 * g + 1] = w1;
            }
        }
    }
    __syncthreads();

    // ---- hoist Phase B: dynamic chunk of C2 = 2*ceil(Lv/8) entries ----
    // 4 threads per (n,v); kk-th thread takes entries [kk*C2, kk*C2+C2)
    // of the (n,v) list. 4*C2 <= WLV always; overflow reads hit sentinels.
    unsigned int bpk[14];
    int bW = 0;
    const int bn = tid >> 3, bk = tid & 7;
    if (bn < NN) {
        const int v  = bk >> 2, kk = bk & 3;
        const int Lv = lvn[bn][v];
        const int C2 = ((Lv + 7) >> 3) << 1;         // even, <= 28
        bW = C2 >> 1;                                // words, <= 14
        const unsigned int* src =
            (const unsigned int*)(wl + bn * WLN + v * WLV + kk * C2);
        #pragma unroll
        for (int i = 0; i < 14; ++i)
            bpk[i] = (i < bW) ? src[i] : 0x01F801F8u;
    }

    const float f12 = spw * (1.0f / 12.0f);

    for (int it = 0; it < NIT; ++it) {
        // ---- Phase A: min1/min2/sign per (vs, check), 2 threads/check ----
        if (aW > 0) {
            float m1a = 1e30f, m2a = 1e30f, m1b = 1e30f, m2b = 1e30f;
            unsigned int sb = 0u;
            #pragma unroll
            for (int g = 0; g < 8; ++g) {
                if (g < aW) {
                    unsigned int w0 = apk[2 * g], w1 = apk[2 * g + 1];
                    float x0 = *(const float*)((const char*)base0 + (w0 & 0xffffu));
                    float x1 = *(const float*)((const char*)base0 + (w0 >> 16));
                    float x2 = *(const float*)((const char*)base0 + (w1 & 0xffffu));
                    float x3 = *(const float*)((const char*)base0 + (w1 >> 16));
                    sb ^= __float_as_uint(x0) ^ __float_as_uint(x1)
                        ^ __float_as_uint(x2) ^ __float_as_uint(x3);
                    float a0 = fabsf(x0), a1 = fabsf(x1);
                    float a2 = fabsf(x2), a3 = fabsf(x3);
                    m2a = fminf(m2a, fmaxf(a0, m1a)); m1a = fminf(m1a, a0);
                    m2b = fminf(m2b, fmaxf(a1, m1b)); m1b = fminf(m1b, a1);
                    m2a = fminf(m2a, fmaxf(a2, m1a)); m1a = fminf(m1a, a2);
                    m2b = fminf(m2b, fmaxf(a3, m1b)); m1b = fminf(m1b, a3);
                }
            }
            float m1 = fminf(m1a, m1b);
            float m2 = fminf(fminf(m2a, m2b), fmaxf(m1a, m1b));
            float om1 = __shfl_xor(m1, 1);
            float om2 = __shfl_xor(m2, 1);
            unsigned int osb = (unsigned int)__shfl_xor((int)sb, 1);
            float mm1 = fminf(m1, om1);
            float mm2 = fminf(fminf(m2, om2), fmaxf(m1, om1));
            sb ^= osb;
            float rs = (sb & 0x80000000u) ? -1.0f : 1.0f;
            rs = (mm1 == 0.0f) ? 0.0f : rs;
            if ((tid & 1) == 0) pqf[pqslot] = make_float2(rs * mm1, rs * mm2);
        }
        __syncthreads();

        // ---- Phase B + combine: 8 threads per n, guarded dynamic chunks ----
        if (bn < NN) {
            const float x = base0[bn];
            float acc = 0.0f;
            #pragma unroll
            for (int i = 0; i < 14; ++i) {
                if (i < bW) {
                    unsigned int w = bpk[i];
                    float2 p0 = *(const float2*)((const char*)pqf + (w & 0xffffu));
                    float2 p1 = *(const float2*)((const char*)pqf + (w >> 16));
                    acc += (fabsf(x) > fabsf(p0.x)) ? p0.x : p0.y;
                    acc += (fabsf(x) > fabsf(p1.x)) ? p1.x : p1.y;
                }
            }
            if (bk >= 4) acc += acc;                 // variant-1 counts twice
            acc += __shfl_xor(acc, 1);
            acc += __shfl_xor(acc, 2);
            acc += __shfl_xor(acc, 4);
            if (bk == 0) {
                float sx = (x > 0.0f) ? 1.0f : ((x < 0.0f) ? -1.0f : 0.0f);
                float ns = fmaf(f12 * sx, acc, x);
                base0[bn] = ns;
                hist[it][bn] = ns;
            }
        }
        __syncthreads();
    }

    // ---- epilogue: coalesced out-writes for iterations 1..3 ----
    if (tid < NIT * NN) {
        int itx = tid / NN;
        int n   = tid - itx * NN;
        out[(size_t)(itx + 1) * (BB * NN) + b * NN + n] = hist[itx][n];
    }

    // ---- fused loss; one global atomic per block ----
    float term = 0.0f;
    if (tid < NN) {
        float sft = base0[tid];
        float sg  = (sft > 0.0f) ? 1.0f : ((sft < 0.0f) ? -1.0f : 0.0f);
        float w   = (sg != (1.0f - 2.0f * lf)) ? 2.0f : 1.0f;
        float z   = -sft;
        term = w * (fmaxf(z, 0.0f) - z * lf + log1pf(expf(-fabsf(z))));
    }
    if (tid < 128) {
        #pragma unroll
        for (int off = 32; off > 0; off >>= 1) term += __shfl_down(term, off);
        if ((tid & 63) == 0) red2[tid >> 6] = term;
    }
    __syncthreads();
    if (tid == 0) atomicAdd(&out[4 * BB * NN], red2[0] + red2[1]);
}

extern "C" void kernel_launch(void* const* d_in, const int* in_sizes, int n_in,
                              void* d_out, int out_size, void* d_ws, size_t ws_size,
                              hipStream_t stream) {
    const float* soft   = (const float*)d_in[0];
    const int*   labels = (const int*)  d_in[1];
    const float* H      = (const float*)d_in[2];
    const float* cw     = (const float*)d_in[3];
    float* outp = (float*)d_out;

    // zero the loss accumulator slot (graph-capturable async memset)
    hipMemsetAsync(outp + 4 * BB * NN, 0, sizeof(float), stream);
    decode_kernel<<<BB, 1024, 0, stream>>>(soft, labels, H, cw, outp);
}

// Round 8
// 82.958 us; speedup vs baseline: 1.0486x; 1.0486x over previous
//
#include <hip/hip_runtime.h>
#include <math.h>

#define MM 63
#define NN 127
#define BB 256
#define NIT 3
#define CSRB 64    // 16 words; row support <= 64 (2 + Binom(125,0.25), P(>64)~1e-10)
#define CSCB 44    // 11 words; col support <= 44 (proven r4)
#define PQS 65     // float2 slots per (v,s) group (odd stride)

__global__ __launch_bounds__(1024)
void decode_kernel(const float* __restrict__ soft_in,
                   const int* __restrict__ labels,
                   const float* __restrict__ Hg,
                   const float* __restrict__ cw,
                   float* __restrict__ out)
{
    const int b   = blockIdx.x;
    const int tid = threadIdx.x;

    __shared__ unsigned char csr[MM][CSRB];
    __shared__ unsigned char csc[NN][CSCB];
    __shared__ int   rcnt[MM], ccnt[NN];
    __shared__ float base0[NN + 1];        // [127] = +1e30 sentinel
    __shared__ float2 pq[8 * PQS];         // (v*4+s)*PQS + m ; m==63 zero slot
    __shared__ float hist[NIT][NN];
    __shared__ float red2[2];

    // ---- prologue: sentinel fills, zero counts, load soft, outs[0] ----
    {
        unsigned int* w1 = (unsigned int*)&csr[0][0];
        for (int i = tid; i < MM * CSRB / 4; i += 1024) w1[i] = 0x7f7f7f7fu;
        unsigned int* w2 = (unsigned int*)&csc[0][0];
        for (int i = tid; i < NN * CSCB / 4; i += 1024) w2[i] = 0x3f3f3f3fu;
    }
    if (tid < MM) rcnt[tid] = 0;
    if (tid < NN) ccnt[tid] = 0;
    float lf = 0.0f;
    if (tid < NN) {
        float v = soft_in[b * NN + tid];
        base0[tid] = v;
        out[b * NN + tid] = v;                       // outs[0]
        lf = (float)labels[b * NN + tid];            // prefetch for loss
    }
    if (tid == NN) base0[NN] = 1e30f;
    if (tid >= 512 && tid < 520)
        pq[(tid - 512) * PQS + 63] = make_float2(0.0f, 0.0f);
    const float spw = log1pf(expf(cw[0]));           // softplus(check_weight)
    __syncthreads();

    // ---- build CSR/CSC: coalesced H scan + LDS atomic append ----
    for (int i = tid; i < MM * NN; i += 1024) {
        if (Hg[i] != 0.0f) {
            int m = i / NN;
            int c = i - m * NN;
            int pr = atomicAdd(&rcnt[m], 1);
            csr[m][pr] = (unsigned char)c;
            int pc = atomicAdd(&ccnt[c], 1);
            csc[c][pc] = (unsigned char)m;
        }
    }
    __syncthreads();

    // ---- hoist Phase-A state: pre-mapped index words (iteration-invariant) ----
    // task: vs = tid>>7 (v=vs>>2, s=vs&3), mslot=(tid>>1)&63, half=tid&1
    unsigned int aw[8];
    int aH2 = 0, aPQ = 0;
    {
        const int vs    = tid >> 7;
        const int mslot = (tid >> 1) & 63;
        const int half  = tid & 1;
        #pragma unroll
        for (int e = 0; e < 8; ++e) aw[e] = 0x7f7f7f7fu;
        if (mslot < MM) {
            const int v     = vs >> 2;
            const int shift = (vs & 3) * 31;
            const int cnt   = rcnt[mslot];
            aH2 = (cnt + 7) >> 3;                    // words per half (<=8)
            aPQ = vs * PQS + mslot;
            const unsigned int* wp = (const unsigned int*)&csr[mslot][0];
            #pragma unroll
            for (int e = 0; e < 8; ++e) {
                if (e < aH2) {
                    unsigned int w = wp[half * aH2 + e];
                    unsigned int o = 0;
                    #pragma unroll
                    for (int j = 0; j < 4; ++j) {
                        int c = (w >> (8 * j)) & 255;
                        int t = c - shift; t += (t < 0) ? NN : 0;   // roll
                        if (v) { t <<= 1; t -= (t >= NN) ? NN : 0; } // perm
                        t = (c == 127) ? 127 : t;                    // sentinel
                        o |= (unsigned int)t << (8 * j);
                    }
                    aw[e] = o;
                }
            }
        }
    }

    // ---- hoist Phase-B state: csc words + pq base (iteration-invariant) ----
    // task: n = tid>>3, k = tid&7 (v=k>>2, s=k&3)
    unsigned int bw[11];
    int bC2 = 0, bn = 0, bDouble = 0;
    const float2* bPqs = pq;
    {
        const int n = tid >> 3;
        const int k = tid & 7;
        #pragma unroll
        for (int e = 0; e < 11; ++e) bw[e] = 0x3f3f3f3fu;
        if (n < NN) {
            const int v = k >> 2;
            const int s = k & 3;
            int p0 = v ? ((n * 64) % NN) : n;
            int j = p0 + s * 31; j -= (j >= NN) ? NN : 0;
            bC2 = (ccnt[j] + 3) >> 2;                // words (<=11)
            bn = n; bDouble = v;
            bPqs = &pq[((v << 2) | s) * PQS];
            const unsigned int* cwp = (const unsigned int*)&csc[j][0];
            #pragma unroll
            for (int e = 0; e < 11; ++e)
                if (e < bC2) bw[e] = cwp[e];
        }
    }

    const float f12 = spw * (1.0f / 12.0f);

    for (int it = 0; it < NIT; ++it) {
        // ---- Phase A: reads base0 via hoisted pre-mapped indices ----
        if (aH2 > 0) {
            float m1 = 1e30f, m2 = 1e30f;
            unsigned int sb = 0u;
            #pragma unroll
            for (int e = 0; e < 8; ++e) {
                if (e < aH2) {
                    unsigned int w = aw[e];
                    #pragma unroll
                    for (int j = 0; j < 4; ++j) {
                        int idx = (w >> (8 * j)) & 255;
                        float x = base0[idx];
                        float a = __uint_as_float(__float_as_uint(x) & 0x7fffffffu);
                        sb ^= __float_as_uint(x);
                        m2 = fminf(m2, fmaxf(a, m1));
                        m1 = fminf(m1, a);
                    }
                }
            }
            float om1 = __shfl_xor(m1, 1);
            float om2 = __shfl_xor(m2, 1);
            unsigned int osb = (unsigned int)__shfl_xor((int)sb, 1);
            float mm2 = fminf(fminf(m2, om2), fmaxf(m1, om1));
            float mm1 = fminf(m1, om1);
            sb ^= osb;
            float rs = (sb & 0x80000000u) ? -1.0f : 1.0f;
            rs = (mm1 == 0.0f) ? 0.0f : rs;
            if ((tid & 1) == 0)
                pq[aPQ] = make_float2(rs * mm1, rs * mm2);
        }
        __syncthreads();

        // ---- Phase B + combine via hoisted words; in-place base0 update ----
        if (bC2 > 0) {
            const float x = base0[bn];
            const float a = fabsf(x);
            float acc = 0.0f;
            #pragma unroll
            for (int e = 0; e < 11; ++e) {
                if (e < bC2) {
                    unsigned int w = bw[e];
                    #pragma unroll
                    for (int j = 0; j < 4; ++j) {
                        int m = (w >> (8 * j)) & 255;
                        float2 pv = bPqs[m];
                        acc += (a > fabsf(pv.x)) ? pv.x : pv.y;
                    }
                }
            }
            if (bDouble) acc += acc;                 // t2 counts twice
            acc += __shfl_xor(acc, 1);
            acc += __shfl_xor(acc, 2);
            acc += __shfl_xor(acc, 4);
            if ((tid & 7) == 0) {
                float sx = (x > 0.0f) ? 1.0f : ((x < 0.0f) ? -1.0f : 0.0f);
                float ns = fmaf(f12 * sx, acc, x);
                base0[bn] = ns;
                hist[it][bn] = ns;                   // defer global store
            }
        }
        __syncthreads();
    }

    // ---- epilogue: coalesced out-writes for iterations 1..3 ----
    if (tid < NIT * NN) {
        int itx = tid / NN;
        int n   = tid - itx * NN;
        out[(size_t)(itx + 1) * (BB * NN) + b * NN + n] = hist[itx][n];
    }

    // ---- fused loss; one global atomic per block ----
    float term = 0.0f;
    if (tid < NN) {
        float sft = base0[tid];
        float sg  = (sft > 0.0f) ? 1.0f : ((sft < 0.0f) ? -1.0f : 0.0f);
        float w   = (sg != (1.0f - 2.0f * lf)) ? 2.0f : 1.0f;
        float z   = -sft;
        term = w * (fmaxf(z, 0.0f) - z * lf + log1pf(expf(-fabsf(z))));
    }
    if (tid < 128) {
        #pragma unroll
        for (int off = 32; off > 0; off >>= 1)
            term += __shfl_down(term, off);
        if ((tid & 63) == 0) red2[tid >> 6] = term;
    }
    __syncthreads();
    if (tid == 0) atomicAdd(&out[4 * BB * NN], red2[0] + red2[1]);
}

extern "C" void kernel_launch(void* const* d_in, const int* in_sizes, int n_in,
                              void* d_out, int out_size, void* d_ws, size_t ws_size,
                              hipStream_t stream) {
    const float* soft   = (const float*)d_in[0];
    const int*   labels = (const int*)  d_in[1];
    const float* H      = (const float*)d_in[2];
    const float* cw     = (const float*)d_in[3];
    float* outp = (float*)d_out;

    // zero the loss accumulator slot (graph-capturable async memset)
    hipMemsetAsync(outp + 4 * BB * NN, 0, sizeof(float), stream);
    decode_kernel<<<BB, 1024, 0, stream>>>(soft, labels, H, cw, outp);
}